// Round 1
// baseline (50.777 us; speedup 1.0000x reference)
//
#include <hip/hip_runtime.h>
#include <hip/hip_bf16.h>

typedef __attribute__((ext_vector_type(8))) short bf16x8;
typedef __attribute__((ext_vector_type(4))) float f32x4;

#define NB 8192
#define NS 8

__device__ __forceinline__ unsigned short f2bf(float f) {
  union { float f; unsigned int u; } v; v.f = f;
  unsigned int r = v.u + 0x7FFFu + ((v.u >> 16) & 1u);
  return (unsigned short)(r >> 16);
}

// Prep: W2 (64x1024 f32) -> bf16 in MFMA B-fragment order; Wc = [W_emb;b_emb] @ W1[0:64,:]
__global__ __launch_bounds__(256) void prep_kernel(
    const float* __restrict__ W2, const float* __restrict__ W_emb,
    const float* __restrict__ b_emb, const float* __restrict__ W1,
    unsigned short* __restrict__ w2f, float* __restrict__ wc) {
  int tid = blockIdx.x * 256 + threadIdx.x;
  if (tid < 8192) {
    // granule tid = (ntile*2 + kstep)*64 + lane
    int lane = tid & 63;
    int ks = (tid >> 6) & 1;
    int nt = tid >> 7;
    int col = nt * 16 + (lane & 15);
    int k0 = ks * 32 + (lane >> 4) * 8;
    bf16x8 pk;
#pragma unroll
    for (int e = 0; e < 8; ++e)
      pk[e] = (short)f2bf(W2[(k0 + e) * 1024 + col]);
    *(bf16x8*)(w2f + tid * 8) = pk;
  } else if (tid < 8192 + 192) {
    int t2 = tid - 8192;
    int c = t2 >> 6, k = t2 & 63;
    float s = 0.f;
    for (int e = 0; e < 64; ++e) {
      float src = (c < 2) ? W_emb[c * 64 + e] : b_emb[e];
      s += src * W1[e * 64 + k];
    }
    wc[t2] = s;  // wc[0][k], wc[1][k], cbe[k]
  }
}

// Main: one block per group. A = relu(rel@Wc + hW) built in LDS in fragment order,
// then 256x1024x64 bf16 MFMA GEMM with fused max-pool over the 16 rows of each M-tile.
__global__ __launch_bounds__(256, 2) void pool_kernel(
    const float* __restrict__ in_xy, const float* __restrict__ h_states,
    const float* __restrict__ W1, const float* __restrict__ b1,
    const float* __restrict__ b2, const unsigned short* __restrict__ w2f,
    const float* __restrict__ wc, float* __restrict__ out) {
  __shared__ bf16x8 Afrag[2048];     // 32 KB, fragment-ordered A (256x64 bf16)
  __shared__ float hW[16 * 68];      // padded rows (68) to spread banks
  __shared__ float exy[32];          // x[0:16], y[16:32]
  const int g = blockIdx.x;
  const int t = threadIdx.x;
  const int lane = t & 63;
  const int wv = t >> 6;

  if (t < 32) {
    int p = t & 15;
    exy[t] = in_xy[((NS - 1) * NB + g * 16 + p) * 2 + (t >> 4)];
  }

  // hW[j][k] = b1[k] + cbe[k] + sum_e h[g*16+j][e] * W1[64+e][k]
  {
    int k = t & 63;
    int j0 = t >> 6;  // wave-uniform
    const float* hbase = h_states + g * 16 * 64;
    float a0 = 0.f, a1 = 0.f, a2 = 0.f, a3 = 0.f;
    for (int e = 0; e < 64; ++e) {
      float w = W1[(64 + e) * 64 + k];
      a0 += hbase[(j0) * 64 + e] * w;
      a1 += hbase[(j0 + 4) * 64 + e] * w;
      a2 += hbase[(j0 + 8) * 64 + e] * w;
      a3 += hbase[(j0 + 12) * 64 + e] * w;
    }
    float bb = b1[k] + wc[128 + k];
    hW[(j0) * 68 + k] = a0 + bb;
    hW[(j0 + 4) * 68 + k] = a1 + bb;
    hW[(j0 + 8) * 68 + k] = a2 + bb;
    hW[(j0 + 12) * 68 + k] = a3 + bb;
  }

  // B fragments (resident in VGPRs) + bias, independent of LDS above
  bf16x8 bfr[16][2];
  float b2v[16];
#pragma unroll
  for (int u = 0; u < 16; ++u) {
    int nt = wv * 16 + u;
    bfr[u][0] = *(const bf16x8*)(w2f + ((nt * 2 + 0) * 64 + lane) * 8);
    bfr[u][1] = *(const bf16x8*)(w2f + ((nt * 2 + 1) * 64 + lane) * 8);
    b2v[u] = b2[nt * 16 + (lane & 15)];
  }
  __syncthreads();

  // A build: thread t writes granules t + 256*c (fixed j = t&15, fixed k-chunk, i = (t>>7)+2c)
  {
    int j = t & 15;
    int kc = (t >> 4) & 3;
    int ks = (t >> 6) & 1;
    int k0 = ks * 32 + kc * 8;
    int mb = t >> 7;
    float w0[8], w1[8], hv[8];
#pragma unroll
    for (int e = 0; e < 8; ++e) {
      w0[e] = wc[k0 + e];
      w1[e] = wc[64 + k0 + e];
      hv[e] = hW[j * 68 + k0 + e];
    }
    float exj = exy[j], eyj = exy[16 + j];
#pragma unroll
    for (int c = 0; c < 8; ++c) {
      int m = mb + 2 * c;  // i index
      float rx = exj - exy[m];
      float ry = eyj - exy[16 + m];
      bf16x8 pk;
#pragma unroll
      for (int e = 0; e < 8; ++e) {
        float v = rx * w0[e] + ry * w1[e] + hv[e];
        v = fmaxf(v, 0.f);
        pk[e] = (short)f2bf(v);
      }
      Afrag[t + 256 * c] = pk;
    }
  }
  __syncthreads();

  // GEMM + fused pool. Wave wv owns 256 cols (ntiles wv*16..wv*16+15).
  const int obase = (g * 16) * 1024 + wv * 256 + (lane & 15);
  for (int m = 0; m < 16; ++m) {
    bf16x8 a0 = Afrag[(m * 2 + 0) * 64 + lane];
    bf16x8 a1 = Afrag[(m * 2 + 1) * 64 + lane];
    f32x4 acc[16];
#pragma unroll
    for (int u = 0; u < 16; ++u) {
      f32x4 z = {0.f, 0.f, 0.f, 0.f};
      acc[u] = __builtin_amdgcn_mfma_f32_16x16x32_bf16(a0, bfr[u][0], z, 0, 0, 0);
    }
#pragma unroll
    for (int u = 0; u < 16; ++u)
      acc[u] = __builtin_amdgcn_mfma_f32_16x16x32_bf16(a1, bfr[u][1], acc[u], 0, 0, 0);
#pragma unroll
    for (int u = 0; u < 16; ++u) {
      float mx = fmaxf(fmaxf(acc[u][0], acc[u][1]), fmaxf(acc[u][2], acc[u][3]));
      mx = fmaxf(mx, __shfl_xor(mx, 16));
      mx = fmaxf(mx, __shfl_xor(mx, 32));
      if (lane < 16) out[obase + m * 1024 + u * 16] = fmaxf(mx + b2v[u], 0.f);
    }
  }
}

extern "C" void kernel_launch(void* const* d_in, const int* in_sizes, int n_in,
                              void* d_out, int out_size, void* d_ws, size_t ws_size,
                              hipStream_t stream) {
  const float* in_xy = (const float*)d_in[0];
  const float* h_states = (const float*)d_in[2];
  const float* W_emb = (const float*)d_in[4];
  const float* b_emb = (const float*)d_in[5];
  const float* W1 = (const float*)d_in[6];
  const float* b1 = (const float*)d_in[7];
  const float* W2 = (const float*)d_in[8];
  const float* b2 = (const float*)d_in[9];
  float* out = (float*)d_out;

  unsigned short* w2f = (unsigned short*)d_ws;            // 131072 B
  float* wc = (float*)((char*)d_ws + 131072);             // 192 f32

  prep_kernel<<<33, 256, 0, stream>>>(W2, W_emb, b_emb, W1, w2f, wc);
  pool_kernel<<<512, 256, 0, stream>>>(in_xy, h_states, W1, b1, b2, w2f, wc, out);
}

// Round 2
// 35.025 us; speedup vs baseline: 1.4497x; 1.4497x over previous
//
#include <hip/hip_runtime.h>
#include <hip/hip_bf16.h>

typedef __attribute__((ext_vector_type(8))) short bf16x8;
typedef __attribute__((ext_vector_type(4))) float f32x4;
typedef __attribute__((ext_vector_type(2))) float f32x2;

#define NB 8192
#define NS 8

__device__ __forceinline__ unsigned short f2bf(float f) {
  union { float f; unsigned int u; } v; v.f = f;
  unsigned int r = v.u + 0x7FFFu + ((v.u >> 16) & 1u);
  return (unsigned short)(r >> 16);
}

// Prep: W2 (64x1024 f32) -> bf16 in MFMA B-fragment order; Wc = [W_emb;b_emb] @ W1[0:64,:]
__global__ __launch_bounds__(256) void prep_kernel(
    const float* __restrict__ W2, const float* __restrict__ W_emb,
    const float* __restrict__ b_emb, const float* __restrict__ W1,
    unsigned short* __restrict__ w2f, float* __restrict__ wc) {
  int tid = blockIdx.x * 256 + threadIdx.x;
  if (tid < 8192) {
    // granule tid = (ntile*2 + kstep)*64 + lane
    int lane = tid & 63;
    int ks = (tid >> 6) & 1;
    int nt = tid >> 7;
    int col = nt * 16 + (lane & 15);
    int k0 = ks * 32 + (lane >> 4) * 8;
    bf16x8 pk;
#pragma unroll
    for (int e = 0; e < 8; ++e)
      pk[e] = (short)f2bf(W2[(k0 + e) * 1024 + col]);
    *(bf16x8*)(w2f + tid * 8) = pk;
  } else if (tid < 8192 + 192) {
    int t2 = tid - 8192;
    int c = t2 >> 6, k = t2 & 63;
    float s = 0.f;
    for (int e = 0; e < 64; ++e) {
      float src = (c < 2) ? W_emb[c * 64 + e] : b_emb[e];
      s += src * W1[e * 64 + k];
    }
    wc[t2] = s;  // wc[0][k], wc[1][k], cbe[k]
  }
}

// Main: one block per group, 8 waves. A = relu(rel@Wc + hW) built in LDS in
// fragment order, then 256x1024x64 bf16 MFMA GEMM; pooling via per-wave-private
// swizzled LDS transpose (no shuffles), full-wave coalesced dwordx2 stores.
__global__ __launch_bounds__(512, 4) void pool_kernel(
    const float* __restrict__ in_xy, const float* __restrict__ h_states,
    const float* __restrict__ W1, const float* __restrict__ b1,
    const float* __restrict__ b2, const unsigned short* __restrict__ w2f,
    const float* __restrict__ wc, float* __restrict__ out) {
  __shared__ bf16x8 Afrag[2048];     // 32 KB, fragment-ordered A (256x64 bf16)
  __shared__ float hW[16 * 68];      // padded rows to spread banks
  __shared__ float exy[32];          // x[0:16], y[16:32]
  __shared__ float pm[8][512];       // per-wave pool scratch: [r=4][128 dwords], swizzled
  const int g = blockIdx.x;
  const int t = threadIdx.x;
  const int lane = t & 63;
  const int wv = t >> 6;

  if (t < 32) {
    int p = t & 15;
    exy[t] = in_xy[((NS - 1) * NB + g * 16 + p) * 2 + (t >> 4)];
  }

  // hW[j][k] = b1[k] + cbe[k] + sum_e h[g*16+j][e] * W1[64+e][k]; 2 rows/thread
  {
    int k = t & 63;
    int j0 = t >> 6;  // 0..7, wave-uniform
    const float* hbase = h_states + g * 16 * 64;
    float a0 = 0.f, a1 = 0.f;
    for (int e = 0; e < 64; ++e) {
      float w = W1[(64 + e) * 64 + k];
      a0 += hbase[j0 * 64 + e] * w;
      a1 += hbase[(j0 + 8) * 64 + e] * w;
    }
    float bb = b1[k] + wc[128 + k];
    hW[j0 * 68 + k] = a0 + bb;
    hW[(j0 + 8) * 68 + k] = a1 + bb;
  }

  // B fragments resident in VGPRs (8 ntiles/wave) + bias pair for epilogue
  bf16x8 bfr[8][2];
#pragma unroll
  for (int u = 0; u < 8; ++u) {
    int nt = wv * 8 + u;
    bfr[u][0] = *(const bf16x8*)(w2f + ((nt * 2 + 0) * 64 + lane) * 8);
    bfr[u][1] = *(const bf16x8*)(w2f + ((nt * 2 + 1) * 64 + lane) * 8);
  }
  f32x2 b2v = *(const f32x2*)(b2 + wv * 128 + lane * 2);
  __syncthreads();

  // A build: thread t writes granules t + 512*c (fixed j=t&15, fixed k-chunk, m=(t>>7)+4c)
  {
    int j = t & 15;
    int kc = (t >> 4) & 3;
    int ks = (t >> 6) & 1;
    int k0 = ks * 32 + kc * 8;
    int mb = t >> 7;  // 0..3
    float w0[8], w1[8], hv[8];
#pragma unroll
    for (int e = 0; e < 8; ++e) {
      w0[e] = wc[k0 + e];
      w1[e] = wc[64 + k0 + e];
      hv[e] = hW[j * 68 + k0 + e];
    }
    float exj = exy[j], eyj = exy[16 + j];
#pragma unroll
    for (int c = 0; c < 4; ++c) {
      int m = mb + 4 * c;  // i index
      float rx = exj - exy[m];
      float ry = eyj - exy[16 + m];
      bf16x8 pk;
#pragma unroll
      for (int e = 0; e < 8; ++e) {
        float v = rx * w0[e] + ry * w1[e] + hv[e];
        v = fmaxf(v, 0.f);
        pk[e] = (short)f2bf(v);
      }
      Afrag[t + 512 * c] = pk;
    }
  }
  __syncthreads();

  // GEMM + fused pool. Wave wv owns 128 cols (ntiles wv*8 .. wv*8+7).
  float* pmw = &pm[wv][0];
  const int r = lane >> 4, cc = lane & 15;            // pm write coords
  const int ru = lane >> 3, rc = (2 * lane) & 15;     // pm read coords
  const int obase = (g * 16) * 1024 + wv * 128 + lane * 2;
  for (int m = 0; m < 16; ++m) {
    bf16x8 a0 = Afrag[(m * 2 + 0) * 64 + lane];
    bf16x8 a1 = Afrag[(m * 2 + 1) * 64 + lane];
    f32x4 acc[8];
#pragma unroll
    for (int u = 0; u < 8; ++u) {
      f32x4 z = {0.f, 0.f, 0.f, 0.f};
      acc[u] = __builtin_amdgcn_mfma_f32_16x16x32_bf16(a0, bfr[u][0], z, 0, 0, 0);
    }
#pragma unroll
    for (int u = 0; u < 8; ++u)
      acc[u] = __builtin_amdgcn_mfma_f32_16x16x32_bf16(a1, bfr[u][1], acc[u], 0, 0, 0);
    // partial max over the 4 regs (rows r*4..r*4+3); write to swizzled pm
#pragma unroll
    for (int u = 0; u < 8; ++u) {
      float mx = fmaxf(fmaxf(acc[u][0], acc[u][1]), fmaxf(acc[u][2], acc[u][3]));
      pmw[r * 128 + (((u ^ r) << 4) | cc)] = mx;
    }
    // flush: lane-transposed read (b64), reduce over r, bias+relu, coalesced store
    f32x2 v0 = *(const f32x2*)&pmw[0 * 128 + (((ru ^ 0) << 4) | rc)];
    f32x2 v1 = *(const f32x2*)&pmw[1 * 128 + (((ru ^ 1) << 4) | rc)];
    f32x2 v2 = *(const f32x2*)&pmw[2 * 128 + (((ru ^ 2) << 4) | rc)];
    f32x2 v3 = *(const f32x2*)&pmw[3 * 128 + (((ru ^ 3) << 4) | rc)];
    float o0 = fmaxf(fmaxf(v0[0], v1[0]), fmaxf(v2[0], v3[0]));
    float o1 = fmaxf(fmaxf(v0[1], v1[1]), fmaxf(v2[1], v3[1]));
    f32x2 res;
    res[0] = fmaxf(o0 + b2v[0], 0.f);
    res[1] = fmaxf(o1 + b2v[1], 0.f);
    *(f32x2*)(out + obase + m * 1024) = res;
  }
}

extern "C" void kernel_launch(void* const* d_in, const int* in_sizes, int n_in,
                              void* d_out, int out_size, void* d_ws, size_t ws_size,
                              hipStream_t stream) {
  const float* in_xy = (const float*)d_in[0];
  const float* h_states = (const float*)d_in[2];
  const float* W_emb = (const float*)d_in[4];
  const float* b_emb = (const float*)d_in[5];
  const float* W1 = (const float*)d_in[6];
  const float* b1 = (const float*)d_in[7];
  const float* W2 = (const float*)d_in[8];
  const float* b2 = (const float*)d_in[9];
  float* out = (float*)d_out;

  unsigned short* w2f = (unsigned short*)d_ws;            // 131072 B
  float* wc = (float*)((char*)d_ws + 131072);             // 192 f32

  prep_kernel<<<33, 256, 0, stream>>>(W2, W_emb, b_emb, W1, w2f, wc);
  pool_kernel<<<512, 512, 0, stream>>>(in_xy, h_states, W1, b1, b2, w2f, wc, out);
}